// Round 2
// baseline (825.715 us; speedup 1.0000x reference)
//
#include <hip/hip_runtime.h>
#include <hip/hip_bf16.h>
#include <math.h>

#define NN 25000
#define NE 250000
#define DD 64
#define HH 4
#define NGROUP (NE / 16)   // 15625 16-edge groups

typedef __attribute__((ext_vector_type(8))) short bf16x8;
typedef __attribute__((ext_vector_type(4))) float f32x4;

#define WT_LD 136   // 128 + 8 pad (shorts) -> 272B row stride

__device__ __forceinline__ float softplus_f(float x) {
    return fmaxf(x, 0.0f) + __logf(1.0f + __expf(-fabsf(x)));
}

__device__ __forceinline__ unsigned short f2bf(float f) {
    __hip_bfloat16 h = __float2bfloat16(f);
    unsigned short u;
    __builtin_memcpy(&u, &h, 2);
    return u;
}

__device__ __forceinline__ float bf2f(unsigned short u) {
    return __uint_as_float(((unsigned int)u) << 16);
}

// Load 8 consecutive floats, split each into bf16 hi (truncated) + bf16 lo
// (exact remainder, truncated). Pure bit-ops: hi = bits>>16 (1 instr),
// hi_f = bits&0xffff0000, lo = trunc16(v - hi_f). The (hi,lo) pair represents
// v with rel error <= 2^-17 -- same budget as the old double-RNE split at
// ~1/3 the VALU cost.
__device__ __forceinline__ void load8(const float* p, bf16x8& hi, bf16x8& lo) {
    float4 a = *(const float4*)p;
    float4 b = *(const float4*)(p + 4);
    float v[8] = {a.x, a.y, a.z, a.w, b.x, b.y, b.z, b.w};
#pragma unroll
    for (int i = 0; i < 8; ++i) {
        unsigned int u = __float_as_uint(v[i]);
        hi[i] = (short)(u >> 16);
        float hf = __uint_as_float(u & 0xffff0000u);
        lo[i] = (short)(__float_as_uint(v[i] - hf) >> 16);
    }
}

// One wave = 16 edges, mfma_f32_16x16x32_bf16, A gathered straight into lanes,
// W^T bf16 in LDS (one copy shared by the block's waves).
// OCCUPANCY NOTE (r1 lesson): LDS=71680B allows 2 blocks/CU, but the GRID must
// supply 2 blocks per CU. r1 ran 256 blocks on 256 CUs -> 1 block/CU -> 16
// waves/CU cap (occ 35%, same as r0). This round: grid=512 x 1024thr ->
// 2 blocks/CU x 16 waves = 32 waves/CU cap. VGPR=64 == 8 waves/SIMD budget.
__global__ __launch_bounds__(1024, 2)
void k_edge(const float* __restrict__ x, const float* __restrict__ ea,
            const float* __restrict__ W, const float* __restrict__ att,
            const float* __restrict__ bn_g, const float* __restrict__ bn_b,
            const float* __restrict__ bn_m, const float* __restrict__ bn_v,
            const int* __restrict__ eidx,
            unsigned short* __restrict__ outj,
            float* __restrict__ expa)
{
    __shared__ unsigned short Wsh[256 * WT_LD];  // W^T bf16 [n][k], padded
    __shared__ float attI[256], attJ[256];       // bnsc folded in

    const int tid = threadIdx.x;
    const int lane = tid & 63;
    const int q = lane >> 4;      // quad 0..3
    const int r = lane & 15;

    // BN fold: alpha_bn = lg*bnsc + bnsh; bnsc folds into att tables, and
    // exp(softplus(z)) == 1 + exp(z) exactly, so the final softplus dies.
    float bnsc[HH], bnsh[HH];
#pragma unroll
    for (int t = 0; t < HH; ++t) {
        float inv = rsqrtf(bn_v[t] + 1e-5f);
        bnsc[t] = bn_g[t] * inv;
        bnsh[t] = bn_b[t] - bn_m[t] * bn_g[t] * inv;
    }

    // Stage W^T (coalesced read of W[k*256+n], n fast-varying).
    for (int idx = tid; idx < 32768; idx += 1024) {
        int k = idx >> 8, n = idx & 255;
        Wsh[n * WT_LD + k] = f2bf(W[idx]);
    }
    if (tid < 256) {
        int c = tid;
        float sc = bnsc[c >> 6];
        attI[c] = att[(c >> 6) * 128 + (c & 63)] * sc;
        attJ[c] = att[(c >> 6) * 128 + 64 + (c & 63)] * sc;
    }
    __syncthreads();

    const int gw = blockIdx.x * 16 + (tid >> 6);
    const int nw = gridDim.x * 16;

    for (int g = gw; g < NGROUP; g += nw) {
        const int e0 = g * 16;
        const int ei = eidx[e0 + r];
        const int ej = eidx[NE + e0 + r];
        const float* xi = x + (size_t)ei * DD;
        const float* xj = x + (size_t)ej * DD;
        const float* ev = ea + (size_t)(e0 + r) * DD;

        bf16x8 Ahi[6], Alo[6];  // 0,1: x_i k-tiles; 2,3: x_j; 4,5: ea
        load8(xi + q * 8,      Ahi[0], Alo[0]);
        load8(xi + 32 + q * 8, Ahi[1], Alo[1]);
        load8(xj + q * 8,      Ahi[2], Alo[2]);
        load8(xj + 32 + q * 8, Ahi[3], Alo[3]);
        load8(ev + q * 8,      Ahi[4], Alo[4]);
        load8(ev + 32 + q * 8, Ahi[5], Alo[5]);

        float lg[4][4];  // [reg][head]
#pragma unroll
        for (int a = 0; a < 4; ++a)
#pragma unroll
            for (int b = 0; b < 4; ++b) lg[a][b] = 0.f;

        // ---- fused MFMA + epilogue: iteration nt handles col-tiles
        // {nt+4h | h=0..3} (one col per head per lane -> one ushort4 store) ----
#pragma unroll
        for (int nt = 0; nt < 4; ++nt) {
            f32x4 ai[4], aj[4];
#pragma unroll
            for (int h = 0; h < 4; ++h) {
                ai[h] = (f32x4){0.f, 0.f, 0.f, 0.f};
                aj[h] = (f32x4){0.f, 0.f, 0.f, 0.f};
            }
#pragma unroll
            for (int h = 0; h < 4; ++h) {
                const unsigned short* bp = &Wsh[((nt + 4 * h) * 16 + r) * WT_LD + q * 8];
#pragma unroll
                for (int kt = 0; kt < 4; ++kt) {
                    bf16x8 bf = *(const bf16x8*)(bp + kt * 32);
                    const int fi = (kt < 2) ? kt : kt + 2;  // x_i, x_i, ea, ea
                    const int fj = kt + 2;                  // x_j, x_j, ea, ea
                    ai[h] = __builtin_amdgcn_mfma_f32_16x16x32_bf16(Ahi[fi], bf, ai[h], 0, 0, 0);
                    ai[h] = __builtin_amdgcn_mfma_f32_16x16x32_bf16(Alo[fi], bf, ai[h], 0, 0, 0);
                    aj[h] = __builtin_amdgcn_mfma_f32_16x16x32_bf16(Ahi[fj], bf, aj[h], 0, 0, 0);
                    aj[h] = __builtin_amdgcn_mfma_f32_16x16x32_bf16(Alo[fj], bf, aj[h], 0, 0, 0);
                }
            }
            // consume: softplus, att partials, pack+store outj (acc dies here)
            const int dbase = nt * 16 + r;   // dim index d for this lane
#pragma unroll
            for (int reg = 0; reg < 4; ++reg) {
                float sp[4];
#pragma unroll
                for (int h = 0; h < 4; ++h) {
                    const int c = dbase + 64 * h;
                    float spi = softplus_f(ai[h][reg]);
                    float spj = softplus_f(aj[h][reg]);
                    lg[reg][h] += spi * attI[c] + spj * attJ[c];
                    sp[h] = spj;
                }
                // packed RNE bf16 store (v_cvt_pk_bf16_f32 via intrinsic)
                __hip_bfloat162 p01 = __float22bfloat162_rn(float2{sp[0], sp[1]});
                __hip_bfloat162 p23 = __float22bfloat162_rn(float2{sp[2], sp[3]});
                uint2 pk;
                __builtin_memcpy(&pk.x, &p01, 4);
                __builtin_memcpy(&pk.y, &p23, 4);
                const unsigned e = (unsigned)(e0 + q * 4 + reg);
                *(uint2*)&outj[e * 256 + dbase * 4] = pk;
            }
        }

        // ---- logit reduce (within 16-lane r-group) + BN + exp ----
#pragma unroll
        for (int off = 1; off < 16; off <<= 1) {
#pragma unroll
            for (int a = 0; a < 4; ++a)
#pragma unroll
                for (int b = 0; b < 4; ++b)
                    lg[a][b] += __shfl_xor(lg[a][b], off, 64);
        }
        float exv[4][4];
#pragma unroll
        for (int reg = 0; reg < 4; ++reg)
#pragma unroll
            for (int h = 0; h < 4; ++h)
                exv[reg][h] = 1.0f + __expf(lg[reg][h] + bnsh[h]);  // exp(softplus(z)) == 1+e^z

        if (r < 4) {  // lane r handles head r for its quad's 4 edges
#pragma unroll
            for (int reg = 0; reg < 4; ++reg) {
                const int e = e0 + q * 4 + reg;
                expa[e * 4 + r] = exv[reg][r];
            }
        }
    }
}

// ---- CSR build: counting sort of edges by target node i ----
__global__ __launch_bounds__(256)
void k_hist(const int* __restrict__ eidx, int* __restrict__ deg)
{
    const int e = blockIdx.x * 256 + threadIdx.x;
    if (e < NE) atomicAdd(&deg[eidx[e]], 1);
}

// Single-block exclusive scan of deg[NN] -> offs[NN+1].
__global__ __launch_bounds__(1024)
void k_scan(const int* __restrict__ deg, int* __restrict__ offs)
{
    __shared__ int sh[1024];
    const int t = threadIdx.x;
    const int base = t * 25;
    int s = 0;
#pragma unroll
    for (int k = 0; k < 25; ++k) {
        int idx = base + k;
        if (idx < NN) s += deg[idx];
    }
    sh[t] = s;
    __syncthreads();
    for (int off = 1; off < 1024; off <<= 1) {
        int v = (t >= off) ? sh[t - off] : 0;
        __syncthreads();
        sh[t] += v;
        __syncthreads();
    }
    int run = sh[t] - s;   // exclusive prefix for this thread's chunk
#pragma unroll
    for (int k = 0; k < 25; ++k) {
        int idx = base + k;
        if (idx < NN) {
            offs[idx] = run;
            run += deg[idx];
        } else if (idx == NN) {
            offs[NN] = run;   // == NE
        }
    }
}

__global__ __launch_bounds__(256)
void k_fill(const int* __restrict__ eidx, const int* __restrict__ offs,
            int* __restrict__ cursor, int* __restrict__ elist)
{
    const int e = blockIdx.x * 256 + threadIdx.x;
    if (e < NE) {
        const int i = eidx[e];
        const int p = atomicAdd(&cursor[i], 1);
        elist[offs[i] + p] = e;
    }
}

// One wave per node, SINGLE pass: out[d] = 0.25 * sum_h (sum_e exp_eh*outj_ehd)
// / (sum_e exp_eh) -- the per-head weight is separable, so no pre-pass for the
// denominator and no shuffle reduce. 4-wide unroll issues 4 independent outj
// gathers per step (4x MLP on the elist->outj dependent chain).
__global__ __launch_bounds__(256)
void k_aggr(const int* __restrict__ offs, const int* __restrict__ elist,
            const unsigned short* __restrict__ outj,
            const float* __restrict__ expa,
            const float* __restrict__ bias, float* __restrict__ out)
{
    const int n = blockIdx.x * 4 + (threadIdx.x >> 6);
    const int lane = threadIdx.x & 63;
    const int beg = offs[n];
    const int end = offs[n + 1];

    float a0 = 0.f, a1 = 0.f, a2 = 0.f, a3 = 0.f;
    float d0 = 0.f, d1 = 0.f, d2 = 0.f, d3 = 0.f;
    int t = beg;
    for (; t + 4 <= end; t += 4) {
        const int e0 = elist[t], e1 = elist[t + 1];
        const int e2 = elist[t + 2], e3 = elist[t + 3];
        float4 x0 = *(const float4*)&expa[e0 * 4];
        float4 x1 = *(const float4*)&expa[e1 * 4];
        float4 x2 = *(const float4*)&expa[e2 * 4];
        float4 x3 = *(const float4*)&expa[e3 * 4];
        ushort4 v0 = *(const ushort4*)&outj[((unsigned)e0 << 8) | (lane << 2)];
        ushort4 v1 = *(const ushort4*)&outj[((unsigned)e1 << 8) | (lane << 2)];
        ushort4 v2 = *(const ushort4*)&outj[((unsigned)e2 << 8) | (lane << 2)];
        ushort4 v3 = *(const ushort4*)&outj[((unsigned)e3 << 8) | (lane << 2)];
        a0 += x0.x * bf2f(v0.x); a1 += x0.y * bf2f(v0.y);
        a2 += x0.z * bf2f(v0.z); a3 += x0.w * bf2f(v0.w);
        d0 += x0.x; d1 += x0.y; d2 += x0.z; d3 += x0.w;
        a0 += x1.x * bf2f(v1.x); a1 += x1.y * bf2f(v1.y);
        a2 += x1.z * bf2f(v1.z); a3 += x1.w * bf2f(v1.w);
        d0 += x1.x; d1 += x1.y; d2 += x1.z; d3 += x1.w;
        a0 += x2.x * bf2f(v2.x); a1 += x2.y * bf2f(v2.y);
        a2 += x2.z * bf2f(v2.z); a3 += x2.w * bf2f(v2.w);
        d0 += x2.x; d1 += x2.y; d2 += x2.z; d3 += x2.w;
        a0 += x3.x * bf2f(v3.x); a1 += x3.y * bf2f(v3.y);
        a2 += x3.z * bf2f(v3.z); a3 += x3.w * bf2f(v3.w);
        d0 += x3.x; d1 += x3.y; d2 += x3.z; d3 += x3.w;
    }
    for (; t < end; ++t) {
        const int e = elist[t];
        float4 xv = *(const float4*)&expa[e * 4];
        ushort4 v = *(const ushort4*)&outj[((unsigned)e << 8) | (lane << 2)];
        a0 += xv.x * bf2f(v.x); a1 += xv.y * bf2f(v.y);
        a2 += xv.z * bf2f(v.z); a3 += xv.w * bf2f(v.w);
        d0 += xv.x; d1 += xv.y; d2 += xv.z; d3 += xv.w;
    }
    float rsum = 0.f;
    if (end > beg)
        rsum = 0.25f * (a0 / d0 + a1 / d1 + a2 / d2 + a3 / d3);
    out[n * DD + lane] = rsum + bias[lane];
}

extern "C" void kernel_launch(void* const* d_in, const int* in_sizes, int n_in,
                              void* d_out, int out_size, void* d_ws, size_t ws_size,
                              hipStream_t stream)
{
    (void)in_sizes; (void)n_in; (void)out_size; (void)ws_size;
    const float* x    = (const float*)d_in[0];
    const float* ea   = (const float*)d_in[1];
    const float* W    = (const float*)d_in[2];
    const float* att  = (const float*)d_in[3];
    const float* bias = (const float*)d_in[4];
    const float* bn_g = (const float*)d_in[5];
    const float* bn_b = (const float*)d_in[6];
    const float* bn_m = (const float*)d_in[7];
    const float* bn_v = (const float*)d_in[8];
    const int*   eidx = (const int*)d_in[9];
    float* out = (float*)d_out;

    // ws layout:
    //   outj bf16 [E][64][4]            128,000,000 B @ 0
    //   expa f32  [E][4]                  4,000,000 B @ 128,000,000
    //   deg  i32  [N]                       100,000 B @ 132,000,000
    //   cursor i32 [N]                      100,000 B @ 132,100,000
    //   offs i32  [N+1]                     100,004 B @ 132,200,000
    //   elist i32 [E]                     1,000,000 B @ 132,300,032
    char* ws = (char*)d_ws;
    unsigned short* outj = (unsigned short*)ws;
    float* expa  = (float*)(ws + 128000000ull);
    int*   deg    = (int*)(ws + 132000000ull);
    int*   cursor = (int*)(ws + 132100000ull);
    int*   offs   = (int*)(ws + 132200000ull);
    int*   elist  = (int*)(ws + 132300032ull);

    hipMemsetAsync(deg, 0, 200000, stream);   // deg + cursor (contiguous)

    k_hist<<<dim3((NE + 255) / 256), dim3(256), 0, stream>>>(eidx, deg);
    k_scan<<<dim3(1), dim3(1024), 0, stream>>>(deg, offs);
    k_fill<<<dim3((NE + 255) / 256), dim3(256), 0, stream>>>(eidx, offs, cursor, elist);
    k_edge<<<dim3(512), dim3(1024), 0, stream>>>(
        x, ea, W, att, bn_g, bn_b, bn_m, bn_v, eidx, outj, expa);
    k_aggr<<<dim3(NN / 4), dim3(256), 0, stream>>>(offs, elist, outj, expa, bias, out);
}

// Round 3
// 686.557 us; speedup vs baseline: 1.2027x; 1.2027x over previous
//
#include <hip/hip_runtime.h>
#include <hip/hip_bf16.h>
#include <math.h>

#define NN 25000
#define NE 250000
#define DD 64
#define HH 4
#define NGROUP (NE / 16)   // 15625 16-edge groups

typedef __attribute__((ext_vector_type(8))) short bf16x8;
typedef __attribute__((ext_vector_type(4))) float f32x4;

#define WT_LD 136   // 128 + 8 pad (shorts) -> 272B row stride

__device__ __forceinline__ float softplus_f(float x) {
    return fmaxf(x, 0.0f) + __logf(1.0f + __expf(-fabsf(x)));
}

__device__ __forceinline__ unsigned short f2bf(float f) {
    __hip_bfloat16 h = __float2bfloat16(f);
    unsigned short u;
    __builtin_memcpy(&u, &h, 2);
    return u;
}

__device__ __forceinline__ float bf2f(unsigned short u) {
    return __uint_as_float(((unsigned int)u) << 16);
}

// Load 8 consecutive floats, split each into bf16 hi + bf16 lo (compensated).
// r2 LESSON: keep this EXACT r1 form. The r2 "VALU diet" bundle (bit-op split
// + __float22bfloat162_rn pack) caused a 6x FETCH/WRITE blowup (scratch
// round-trips) -> 640us. Proven-good path only.
__device__ __forceinline__ void load8(const float* p, bf16x8& hi, bf16x8& lo) {
    float4 a = *(const float4*)p;
    float4 b = *(const float4*)(p + 4);
    float v[8] = {a.x, a.y, a.z, a.w, b.x, b.y, b.z, b.w};
#pragma unroll
    for (int i = 0; i < 8; ++i) {
        unsigned short h = f2bf(v[i]);
        hi[i] = (short)h;
        lo[i] = (short)f2bf(v[i] - bf2f(h));
    }
}

// One wave = 16 edges, mfma_f32_16x16x32_bf16, A gathered straight into lanes,
// W^T bf16 in LDS (one copy shared by the block's waves).
// Occupancy: LDS=71680B -> 2 blocks/CU; grid=512 x 1024thr supplies them
// (r2 evidence: occ 35->44%). VGPR=64.
// NEW this round: outj/expa are written in CSR (slot) order so the aggregation
// kernel streams them sequentially. slot[e] comes from k_fill.
__global__ __launch_bounds__(1024, 2)
void k_edge(const float* __restrict__ x, const float* __restrict__ ea,
            const float* __restrict__ W, const float* __restrict__ att,
            const float* __restrict__ bn_g, const float* __restrict__ bn_b,
            const float* __restrict__ bn_m, const float* __restrict__ bn_v,
            const int* __restrict__ eidx, const int* __restrict__ slot,
            unsigned short* __restrict__ outj,
            float* __restrict__ expa)
{
    __shared__ unsigned short Wsh[256 * WT_LD];  // W^T bf16 [n][k], padded
    __shared__ float attI[256], attJ[256];       // bn scale folded in

    const int tid = threadIdx.x;
    const int lane = tid & 63;
    const int q = lane >> 4;      // quad 0..3
    const int r = lane & 15;

    // BN fold: logit_bn = lg*bnsc + bnsh; bnsc folds into the att tables and
    // exp(softplus(z)) == 1 + exp(z) exactly, so the final softplus dies.
    float bnsc[HH], bnsh[HH];
#pragma unroll
    for (int t = 0; t < HH; ++t) {
        float inv = rsqrtf(bn_v[t] + 1e-5f);
        bnsc[t] = bn_g[t] * inv;
        bnsh[t] = bn_b[t] - bn_m[t] * bn_g[t] * inv;
    }

    // Stage W^T (coalesced read of W[k*256+n], n fast-varying).
    for (int idx = tid; idx < 32768; idx += 1024) {
        int k = idx >> 8, n = idx & 255;
        Wsh[n * WT_LD + k] = f2bf(W[idx]);
    }
    if (tid < 256) {
        int c = tid;
        float sc = bnsc[c >> 6];
        attI[c] = att[(c >> 6) * 128 + (c & 63)] * sc;
        attJ[c] = att[(c >> 6) * 128 + 64 + (c & 63)] * sc;
    }
    __syncthreads();

    const int gw = blockIdx.x * 16 + (tid >> 6);
    const int nw = gridDim.x * 16;

    for (int g = gw; g < NGROUP; g += nw) {
        const int e0 = g * 16;
        const int ei = eidx[e0 + r];
        const int ej = eidx[NE + e0 + r];
        const float* xi = x + (size_t)ei * DD;
        const float* xj = x + (size_t)ej * DD;
        const float* ev = ea + (size_t)(e0 + r) * DD;

        // CSR slots for the 4 edges this lane stores (edge = e0 + q*4 + reg).
        int sl[4];
#pragma unroll
        for (int reg = 0; reg < 4; ++reg) sl[reg] = slot[e0 + q * 4 + reg];

        bf16x8 Ahi[6], Alo[6];  // 0,1: x_i k-tiles; 2,3: x_j; 4,5: ea
        load8(xi + q * 8,      Ahi[0], Alo[0]);
        load8(xi + 32 + q * 8, Ahi[1], Alo[1]);
        load8(xj + q * 8,      Ahi[2], Alo[2]);
        load8(xj + 32 + q * 8, Ahi[3], Alo[3]);
        load8(ev + q * 8,      Ahi[4], Alo[4]);
        load8(ev + 32 + q * 8, Ahi[5], Alo[5]);

        float lg[4][4];  // [reg][head]
#pragma unroll
        for (int a = 0; a < 4; ++a)
#pragma unroll
            for (int b = 0; b < 4; ++b) lg[a][b] = 0.f;

        // ---- fused MFMA + epilogue: iteration nt handles col-tiles
        // {nt+4h | h=0..3} (one col per head per lane -> one ushort4 store) ----
#pragma unroll
        for (int nt = 0; nt < 4; ++nt) {
            f32x4 ai[4], aj[4];
#pragma unroll
            for (int h = 0; h < 4; ++h) {
                ai[h] = (f32x4){0.f, 0.f, 0.f, 0.f};
                aj[h] = (f32x4){0.f, 0.f, 0.f, 0.f};
            }
#pragma unroll
            for (int h = 0; h < 4; ++h) {
                const unsigned short* bp = &Wsh[((nt + 4 * h) * 16 + r) * WT_LD + q * 8];
#pragma unroll
                for (int kt = 0; kt < 4; ++kt) {
                    bf16x8 bf = *(const bf16x8*)(bp + kt * 32);
                    const int fi = (kt < 2) ? kt : kt + 2;  // x_i, x_i, ea, ea
                    const int fj = kt + 2;                  // x_j, x_j, ea, ea
                    ai[h] = __builtin_amdgcn_mfma_f32_16x16x32_bf16(Ahi[fi], bf, ai[h], 0, 0, 0);
                    ai[h] = __builtin_amdgcn_mfma_f32_16x16x32_bf16(Alo[fi], bf, ai[h], 0, 0, 0);
                    aj[h] = __builtin_amdgcn_mfma_f32_16x16x32_bf16(Ahi[fj], bf, aj[h], 0, 0, 0);
                    aj[h] = __builtin_amdgcn_mfma_f32_16x16x32_bf16(Alo[fj], bf, aj[h], 0, 0, 0);
                }
            }
            // consume: softplus, att partials, pack+store outj (acc dies here)
            const int dbase = nt * 16 + r;   // dim index d for this lane
#pragma unroll
            for (int reg = 0; reg < 4; ++reg) {
                ushort4 pk;
                unsigned short* pkp = (unsigned short*)&pk;
#pragma unroll
                for (int h = 0; h < 4; ++h) {
                    const int c = dbase + 64 * h;
                    float spi = softplus_f(ai[h][reg]);
                    float spj = softplus_f(aj[h][reg]);
                    lg[reg][h] += spi * attI[c] + spj * attJ[c];
                    pkp[h] = f2bf(spj);
                }
                *(ushort4*)&outj[(size_t)(unsigned)sl[reg] * 256 + dbase * 4] = pk;
            }
        }

        // ---- logit reduce (within 16-lane r-group) + BN + exp ----
#pragma unroll
        for (int off = 1; off < 16; off <<= 1) {
#pragma unroll
            for (int a = 0; a < 4; ++a)
#pragma unroll
                for (int b = 0; b < 4; ++b)
                    lg[a][b] += __shfl_xor(lg[a][b], off, 64);
        }
        float exv[4][4];
#pragma unroll
        for (int reg = 0; reg < 4; ++reg)
#pragma unroll
            for (int h = 0; h < 4; ++h)
                exv[reg][h] = 1.0f + __expf(lg[reg][h] + bnsh[h]);  // exp(softplus(z)) == 1+e^z

        if (r < 4) {  // lane r handles head r for its quad's 4 edges
#pragma unroll
            for (int reg = 0; reg < 4; ++reg)
                expa[sl[reg] * 4 + r] = exv[reg][r];
        }
    }
}

// ---- CSR build: counting sort of edges by target node i ----
__global__ __launch_bounds__(256)
void k_hist(const int* __restrict__ eidx, int* __restrict__ deg)
{
    const int e = blockIdx.x * 256 + threadIdx.x;
    if (e < NE) atomicAdd(&deg[eidx[e]], 1);
}

// Single-block exclusive scan of deg[NN] -> offs[NN+1].
__global__ __launch_bounds__(1024)
void k_scan(const int* __restrict__ deg, int* __restrict__ offs)
{
    __shared__ int sh[1024];
    const int t = threadIdx.x;
    const int base = t * 25;
    int s = 0;
#pragma unroll
    for (int k = 0; k < 25; ++k) {
        int idx = base + k;
        if (idx < NN) s += deg[idx];
    }
    sh[t] = s;
    __syncthreads();
    for (int off = 1; off < 1024; off <<= 1) {
        int v = (t >= off) ? sh[t - off] : 0;
        __syncthreads();
        sh[t] += v;
        __syncthreads();
    }
    int run = sh[t] - s;   // exclusive prefix for this thread's chunk
#pragma unroll
    for (int k = 0; k < 25; ++k) {
        int idx = base + k;
        if (idx < NN) {
            offs[idx] = run;
            run += deg[idx];
        } else if (idx == NN) {
            offs[NN] = run;   // == NE
        }
    }
}

// slot[e] = CSR position of edge e (offs[i] + running cursor).
__global__ __launch_bounds__(256)
void k_fill(const int* __restrict__ eidx, const int* __restrict__ offs,
            int* __restrict__ cursor, int* __restrict__ slot)
{
    const int e = blockIdx.x * 256 + threadIdx.x;
    if (e < NE) {
        const int i = eidx[e];
        const int p = atomicAdd(&cursor[i], 1);
        slot[e] = offs[i] + p;
    }
}

// One wave per node, SINGLE sequential pass over the node's CSR range:
// out[d] = 0.25 * sum_h (sum_t exp_th*outj_thd) / (sum_t exp_th) + bias[d].
// outj/expa are already in CSR order -> pure streaming reads (no elist
// indirection, no gathers). r1 lesson: random 512B gathers ran at ~1 TB/s;
// sequential should run near BW ceiling.
__global__ __launch_bounds__(256)
void k_aggr(const int* __restrict__ offs,
            const unsigned short* __restrict__ outj,
            const float* __restrict__ expa,
            const float* __restrict__ bias, float* __restrict__ out)
{
    const int n = blockIdx.x * 4 + (threadIdx.x >> 6);
    const int lane = threadIdx.x & 63;
    const int beg = offs[n];
    const int end = offs[n + 1];

    float a0 = 0.f, a1 = 0.f, a2 = 0.f, a3 = 0.f;
    float d0 = 0.f, d1 = 0.f, d2 = 0.f, d3 = 0.f;
    int t = beg;
    for (; t + 2 <= end; t += 2) {
        float4 x0 = *(const float4*)&expa[(size_t)t * 4];
        float4 x1 = *(const float4*)&expa[(size_t)(t + 1) * 4];
        ushort4 v0 = *(const ushort4*)&outj[((size_t)t << 8) | (lane << 2)];
        ushort4 v1 = *(const ushort4*)&outj[((size_t)(t + 1) << 8) | (lane << 2)];
        a0 += x0.x * bf2f(v0.x); a1 += x0.y * bf2f(v0.y);
        a2 += x0.z * bf2f(v0.z); a3 += x0.w * bf2f(v0.w);
        d0 += x0.x; d1 += x0.y; d2 += x0.z; d3 += x0.w;
        a0 += x1.x * bf2f(v1.x); a1 += x1.y * bf2f(v1.y);
        a2 += x1.z * bf2f(v1.z); a3 += x1.w * bf2f(v1.w);
        d0 += x1.x; d1 += x1.y; d2 += x1.z; d3 += x1.w;
    }
    for (; t < end; ++t) {
        float4 xv = *(const float4*)&expa[(size_t)t * 4];
        ushort4 v = *(const ushort4*)&outj[((size_t)t << 8) | (lane << 2)];
        a0 += xv.x * bf2f(v.x); a1 += xv.y * bf2f(v.y);
        a2 += xv.z * bf2f(v.z); a3 += xv.w * bf2f(v.w);
        d0 += xv.x; d1 += xv.y; d2 += xv.z; d3 += xv.w;
    }
    float rsum = 0.f;
    if (end > beg)
        rsum = 0.25f * (a0 / d0 + a1 / d1 + a2 / d2 + a3 / d3);
    out[n * DD + lane] = rsum + bias[lane];
}

extern "C" void kernel_launch(void* const* d_in, const int* in_sizes, int n_in,
                              void* d_out, int out_size, void* d_ws, size_t ws_size,
                              hipStream_t stream)
{
    (void)in_sizes; (void)n_in; (void)out_size; (void)ws_size;
    const float* x    = (const float*)d_in[0];
    const float* ea   = (const float*)d_in[1];
    const float* W    = (const float*)d_in[2];
    const float* att  = (const float*)d_in[3];
    const float* bias = (const float*)d_in[4];
    const float* bn_g = (const float*)d_in[5];
    const float* bn_b = (const float*)d_in[6];
    const float* bn_m = (const float*)d_in[7];
    const float* bn_v = (const float*)d_in[8];
    const int*   eidx = (const int*)d_in[9];
    float* out = (float*)d_out;

    // ws layout:
    //   outj bf16 [E][64][4] (CSR order) 128,000,000 B @ 0
    //   expa f32  [E][4]     (CSR order)   4,000,000 B @ 128,000,000
    //   deg  i32  [N]                        100,000 B @ 132,000,000
    //   cursor i32 [N]                       100,000 B @ 132,100,000
    //   offs i32  [N+1]                      100,004 B @ 132,200,000
    //   slot i32  [E]                      1,000,000 B @ 132,300,032
    char* ws = (char*)d_ws;
    unsigned short* outj = (unsigned short*)ws;
    float* expa   = (float*)(ws + 128000000ull);
    int*   deg    = (int*)(ws + 132000000ull);
    int*   cursor = (int*)(ws + 132100000ull);
    int*   offs   = (int*)(ws + 132200000ull);
    int*   slot   = (int*)(ws + 132300032ull);

    hipMemsetAsync(deg, 0, 200000, stream);   // deg + cursor (contiguous)

    k_hist<<<dim3((NE + 255) / 256), dim3(256), 0, stream>>>(eidx, deg);
    k_scan<<<dim3(1), dim3(1024), 0, stream>>>(deg, offs);
    k_fill<<<dim3((NE + 255) / 256), dim3(256), 0, stream>>>(eidx, offs, cursor, slot);
    k_edge<<<dim3(512), dim3(1024), 0, stream>>>(
        x, ea, W, att, bn_g, bn_b, bn_m, bn_v, eidx, slot, outj, expa);
    k_aggr<<<dim3(NN / 4), dim3(256), 0, stream>>>(offs, outj, expa, bias, out);
}

// Round 4
// 333.164 us; speedup vs baseline: 2.4784x; 2.0607x over previous
//
#include <hip/hip_runtime.h>
#include <hip/hip_bf16.h>
#include <math.h>

#define NN 25000
#define NE 250000
#define DD 64
#define HH 4
#define NGROUP (NE / 16)   // 15625 16-edge groups

typedef __attribute__((ext_vector_type(8))) short bf16x8;
typedef __attribute__((ext_vector_type(4))) float f32x4;

#define WT_LD 136   // 128 + 8 pad (shorts) -> 272B row stride

__device__ __forceinline__ float softplus_f(float x) {
    return fmaxf(x, 0.0f) + __logf(1.0f + __expf(-fabsf(x)));
}

__device__ __forceinline__ unsigned short f2bf(float f) {
    __hip_bfloat16 h = __float2bfloat16(f);
    unsigned short u;
    __builtin_memcpy(&u, &h, 2);
    return u;
}

__device__ __forceinline__ float bf2f(unsigned short u) {
    return __uint_as_float(((unsigned int)u) << 16);
}

// Load 8 consecutive floats, split each into bf16 hi + bf16 lo (compensated).
__device__ __forceinline__ void load8(const float* p, bf16x8& hi, bf16x8& lo) {
    float4 a = *(const float4*)p;
    float4 b = *(const float4*)(p + 4);
    float v[8] = {a.x, a.y, a.z, a.w, b.x, b.y, b.z, b.w};
#pragma unroll
    for (int i = 0; i < 8; ++i) {
        unsigned short h = f2bf(v[i]);
        hi[i] = (short)h;
        lo[i] = (short)f2bf(v[i] - bf2f(h));
    }
}

// One wave = 16 edges, mfma_f32_16x16x32_bf16, A gathered straight into lanes,
// W^T bf16 in LDS.
// REGISTER-BUDGET NOTE (r3 lesson): regsPerBlock = 131072/CU. At 2048
// threads/CU (r1-r3 configs) the allocator budget is 64 VGPR/thread; this
// kernel's live state (~110) only fit by luck in r0/r1, and r2/r3's small
// additions crossed the cliff -> Ahi/Alo spilled around the MFMAs -> +1.5 GB
// scratch traffic, 3.3x slowdown. THIS round: 512-thr blocks,
// __launch_bounds__(512,2) -> 1024 threads/CU -> 128 VGPR budget, zero spill,
// 2 blocks/CU (LDS 2x71680=143KB fits), 16 waves/CU cap.
__global__ __launch_bounds__(512, 2)
void k_edge(const float* __restrict__ x, const float* __restrict__ ea,
            const float* __restrict__ W, const float* __restrict__ att,
            const float* __restrict__ bn_g, const float* __restrict__ bn_b,
            const float* __restrict__ bn_m, const float* __restrict__ bn_v,
            const int* __restrict__ eidx, const int* __restrict__ slot,
            unsigned short* __restrict__ outj,
            float* __restrict__ expa)
{
    __shared__ unsigned short Wsh[256 * WT_LD];  // W^T bf16 [n][k], padded
    __shared__ float attI[256], attJ[256];       // bn scale folded in

    const int tid = threadIdx.x;
    const int lane = tid & 63;
    const int q = lane >> 4;      // quad 0..3
    const int r = lane & 15;

    // BN fold: logit_bn = lg*bnsc + bnsh; bnsc folds into the att tables and
    // exp(softplus(z)) == 1 + exp(z) exactly, so the final softplus dies.
    float bnsc[HH], bnsh[HH];
#pragma unroll
    for (int t = 0; t < HH; ++t) {
        float inv = rsqrtf(bn_v[t] + 1e-5f);
        bnsc[t] = bn_g[t] * inv;
        bnsh[t] = bn_b[t] - bn_m[t] * bn_g[t] * inv;
    }

    // Stage W^T (coalesced read of W[k*256+n], n fast-varying).
    for (int idx = tid; idx < 32768; idx += 512) {
        int k = idx >> 8, n = idx & 255;
        Wsh[n * WT_LD + k] = f2bf(W[idx]);
    }
    if (tid < 256) {
        int c = tid;
        float sc = bnsc[c >> 6];
        attI[c] = att[(c >> 6) * 128 + (c & 63)] * sc;
        attJ[c] = att[(c >> 6) * 128 + 64 + (c & 63)] * sc;
    }
    __syncthreads();

    const int gw = blockIdx.x * 8 + (tid >> 6);
    const int nw = gridDim.x * 8;

    for (int g = gw; g < NGROUP; g += nw) {
        const int e0 = g * 16;
        const int ei = eidx[e0 + r];
        const int ej = eidx[NE + e0 + r];
        const float* xi = x + (size_t)ei * DD;
        const float* xj = x + (size_t)ej * DD;
        const float* ev = ea + (size_t)(e0 + r) * DD;

        // CSR slots for the 4 edges this lane stores (edge = e0 + q*4 + reg).
        int sl[4];
#pragma unroll
        for (int reg = 0; reg < 4; ++reg) sl[reg] = slot[e0 + q * 4 + reg];

        bf16x8 Ahi[6], Alo[6];  // 0,1: x_i k-tiles; 2,3: x_j; 4,5: ea
        load8(xi + q * 8,      Ahi[0], Alo[0]);
        load8(xi + 32 + q * 8, Ahi[1], Alo[1]);
        load8(xj + q * 8,      Ahi[2], Alo[2]);
        load8(xj + 32 + q * 8, Ahi[3], Alo[3]);
        load8(ev + q * 8,      Ahi[4], Alo[4]);
        load8(ev + 32 + q * 8, Ahi[5], Alo[5]);

        float lg[4][4];  // [reg][head]
#pragma unroll
        for (int a = 0; a < 4; ++a)
#pragma unroll
            for (int b = 0; b < 4; ++b) lg[a][b] = 0.f;

        // ---- fused MFMA + epilogue: iteration nt handles col-tiles
        // {nt+4h | h=0..3} (one col per head per lane -> one ushort4 store) ----
#pragma unroll
        for (int nt = 0; nt < 4; ++nt) {
            f32x4 ai[4], aj[4];
#pragma unroll
            for (int h = 0; h < 4; ++h) {
                ai[h] = (f32x4){0.f, 0.f, 0.f, 0.f};
                aj[h] = (f32x4){0.f, 0.f, 0.f, 0.f};
            }
#pragma unroll
            for (int h = 0; h < 4; ++h) {
                const unsigned short* bp = &Wsh[((nt + 4 * h) * 16 + r) * WT_LD + q * 8];
#pragma unroll
                for (int kt = 0; kt < 4; ++kt) {
                    bf16x8 bf = *(const bf16x8*)(bp + kt * 32);
                    const int fi = (kt < 2) ? kt : kt + 2;  // x_i, x_i, ea, ea
                    const int fj = kt + 2;                  // x_j, x_j, ea, ea
                    ai[h] = __builtin_amdgcn_mfma_f32_16x16x32_bf16(Ahi[fi], bf, ai[h], 0, 0, 0);
                    ai[h] = __builtin_amdgcn_mfma_f32_16x16x32_bf16(Alo[fi], bf, ai[h], 0, 0, 0);
                    aj[h] = __builtin_amdgcn_mfma_f32_16x16x32_bf16(Ahi[fj], bf, aj[h], 0, 0, 0);
                    aj[h] = __builtin_amdgcn_mfma_f32_16x16x32_bf16(Alo[fj], bf, aj[h], 0, 0, 0);
                }
            }
            // consume: softplus, att partials, pack+store outj (acc dies here)
            const int dbase = nt * 16 + r;   // dim index d for this lane
#pragma unroll
            for (int reg = 0; reg < 4; ++reg) {
                ushort4 pk;
                unsigned short* pkp = (unsigned short*)&pk;
#pragma unroll
                for (int h = 0; h < 4; ++h) {
                    const int c = dbase + 64 * h;
                    float spi = softplus_f(ai[h][reg]);
                    float spj = softplus_f(aj[h][reg]);
                    lg[reg][h] += spi * attI[c] + spj * attJ[c];
                    pkp[h] = f2bf(spj);
                }
                *(ushort4*)&outj[(size_t)(unsigned)sl[reg] * 256 + dbase * 4] = pk;
            }
        }

        // ---- logit reduce (within 16-lane r-group) + BN + exp ----
#pragma unroll
        for (int off = 1; off < 16; off <<= 1) {
#pragma unroll
            for (int a = 0; a < 4; ++a)
#pragma unroll
                for (int b = 0; b < 4; ++b)
                    lg[a][b] += __shfl_xor(lg[a][b], off, 64);
        }
        float exv[4][4];
#pragma unroll
        for (int reg = 0; reg < 4; ++reg)
#pragma unroll
            for (int h = 0; h < 4; ++h)
                exv[reg][h] = 1.0f + __expf(lg[reg][h] + bnsh[h]);  // exp(softplus(z)) == 1+e^z

        if (r < 4) {  // lane r handles head r for its quad's 4 edges
#pragma unroll
            for (int reg = 0; reg < 4; ++reg)
                expa[sl[reg] * 4 + r] = exv[reg][r];
        }
    }
}

// ---- CSR build: counting sort of edges by target node i ----
__global__ __launch_bounds__(256)
void k_hist(const int* __restrict__ eidx, int* __restrict__ deg)
{
    const int e = blockIdx.x * 256 + threadIdx.x;
    if (e < NE) atomicAdd(&deg[eidx[e]], 1);
}

// Single-block exclusive scan of deg[NN] -> offs[NN+1].
__global__ __launch_bounds__(1024)
void k_scan(const int* __restrict__ deg, int* __restrict__ offs)
{
    __shared__ int sh[1024];
    const int t = threadIdx.x;
    const int base = t * 25;
    int s = 0;
#pragma unroll
    for (int k = 0; k < 25; ++k) {
        int idx = base + k;
        if (idx < NN) s += deg[idx];
    }
    sh[t] = s;
    __syncthreads();
    for (int off = 1; off < 1024; off <<= 1) {
        int v = (t >= off) ? sh[t - off] : 0;
        __syncthreads();
        sh[t] += v;
        __syncthreads();
    }
    int run = sh[t] - s;   // exclusive prefix for this thread's chunk
#pragma unroll
    for (int k = 0; k < 25; ++k) {
        int idx = base + k;
        if (idx < NN) {
            offs[idx] = run;
            run += deg[idx];
        } else if (idx == NN) {
            offs[NN] = run;   // == NE
        }
    }
}

// slot[e] = CSR position of edge e (offs[i] + running cursor).
__global__ __launch_bounds__(256)
void k_fill(const int* __restrict__ eidx, const int* __restrict__ offs,
            int* __restrict__ cursor, int* __restrict__ slot)
{
    const int e = blockIdx.x * 256 + threadIdx.x;
    if (e < NE) {
        const int i = eidx[e];
        const int p = atomicAdd(&cursor[i], 1);
        slot[e] = offs[i] + p;
    }
}

// One wave per node, single sequential pass over the node's CSR range:
// out[d] = 0.25 * sum_h (sum_t exp_th*outj_thd) / (sum_t exp_th) + bias[d].
// outj/expa already in CSR order -> pure streaming reads. 4-wide unroll for
// memory-level parallelism.
__global__ __launch_bounds__(256)
void k_aggr(const int* __restrict__ offs,
            const unsigned short* __restrict__ outj,
            const float* __restrict__ expa,
            const float* __restrict__ bias, float* __restrict__ out)
{
    const int n = blockIdx.x * 4 + (threadIdx.x >> 6);
    const int lane = threadIdx.x & 63;
    const int beg = offs[n];
    const int end = offs[n + 1];

    float a0 = 0.f, a1 = 0.f, a2 = 0.f, a3 = 0.f;
    float d0 = 0.f, d1 = 0.f, d2 = 0.f, d3 = 0.f;
    int t = beg;
    for (; t + 4 <= end; t += 4) {
        float4 x0 = *(const float4*)&expa[(size_t)t * 4];
        float4 x1 = *(const float4*)&expa[(size_t)(t + 1) * 4];
        float4 x2 = *(const float4*)&expa[(size_t)(t + 2) * 4];
        float4 x3 = *(const float4*)&expa[(size_t)(t + 3) * 4];
        ushort4 v0 = *(const ushort4*)&outj[((size_t)t << 8) | (lane << 2)];
        ushort4 v1 = *(const ushort4*)&outj[((size_t)(t + 1) << 8) | (lane << 2)];
        ushort4 v2 = *(const ushort4*)&outj[((size_t)(t + 2) << 8) | (lane << 2)];
        ushort4 v3 = *(const ushort4*)&outj[((size_t)(t + 3) << 8) | (lane << 2)];
        a0 += x0.x * bf2f(v0.x); a1 += x0.y * bf2f(v0.y);
        a2 += x0.z * bf2f(v0.z); a3 += x0.w * bf2f(v0.w);
        d0 += x0.x; d1 += x0.y; d2 += x0.z; d3 += x0.w;
        a0 += x1.x * bf2f(v1.x); a1 += x1.y * bf2f(v1.y);
        a2 += x1.z * bf2f(v1.z); a3 += x1.w * bf2f(v1.w);
        d0 += x1.x; d1 += x1.y; d2 += x1.z; d3 += x1.w;
        a0 += x2.x * bf2f(v2.x); a1 += x2.y * bf2f(v2.y);
        a2 += x2.z * bf2f(v2.z); a3 += x2.w * bf2f(v2.w);
        d0 += x2.x; d1 += x2.y; d2 += x2.z; d3 += x2.w;
        a0 += x3.x * bf2f(v3.x); a1 += x3.y * bf2f(v3.y);
        a2 += x3.z * bf2f(v3.z); a3 += x3.w * bf2f(v3.w);
        d0 += x3.x; d1 += x3.y; d2 += x3.z; d3 += x3.w;
    }
    for (; t < end; ++t) {
        float4 xv = *(const float4*)&expa[(size_t)t * 4];
        ushort4 v = *(const ushort4*)&outj[((size_t)t << 8) | (lane << 2)];
        a0 += xv.x * bf2f(v.x); a1 += xv.y * bf2f(v.y);
        a2 += xv.z * bf2f(v.z); a3 += xv.w * bf2f(v.w);
        d0 += xv.x; d1 += xv.y; d2 += xv.z; d3 += xv.w;
    }
    float rsum = 0.f;
    if (end > beg)
        rsum = 0.25f * (a0 / d0 + a1 / d1 + a2 / d2 + a3 / d3);
    out[n * DD + lane] = rsum + bias[lane];
}

extern "C" void kernel_launch(void* const* d_in, const int* in_sizes, int n_in,
                              void* d_out, int out_size, void* d_ws, size_t ws_size,
                              hipStream_t stream)
{
    (void)in_sizes; (void)n_in; (void)out_size; (void)ws_size;
    const float* x    = (const float*)d_in[0];
    const float* ea   = (const float*)d_in[1];
    const float* W    = (const float*)d_in[2];
    const float* att  = (const float*)d_in[3];
    const float* bias = (const float*)d_in[4];
    const float* bn_g = (const float*)d_in[5];
    const float* bn_b = (const float*)d_in[6];
    const float* bn_m = (const float*)d_in[7];
    const float* bn_v = (const float*)d_in[8];
    const int*   eidx = (const int*)d_in[9];
    float* out = (float*)d_out;

    // ws layout:
    //   outj bf16 [E][64][4] (CSR order) 128,000,000 B @ 0
    //   expa f32  [E][4]     (CSR order)   4,000,000 B @ 128,000,000
    //   deg  i32  [N]                        100,000 B @ 132,000,000
    //   cursor i32 [N]                       100,000 B @ 132,100,000
    //   offs i32  [N+1]                      100,004 B @ 132,200,000
    //   slot i32  [E]                      1,000,000 B @ 132,300,032
    char* ws = (char*)d_ws;
    unsigned short* outj = (unsigned short*)ws;
    float* expa   = (float*)(ws + 128000000ull);
    int*   deg    = (int*)(ws + 132000000ull);
    int*   cursor = (int*)(ws + 132100000ull);
    int*   offs   = (int*)(ws + 132200000ull);
    int*   slot   = (int*)(ws + 132300032ull);

    hipMemsetAsync(deg, 0, 200000, stream);   // deg + cursor (contiguous)

    k_hist<<<dim3((NE + 255) / 256), dim3(256), 0, stream>>>(eidx, deg);
    k_scan<<<dim3(1), dim3(1024), 0, stream>>>(deg, offs);
    k_fill<<<dim3((NE + 255) / 256), dim3(256), 0, stream>>>(eidx, offs, cursor, slot);
    k_edge<<<dim3(512), dim3(512), 0, stream>>>(
        x, ea, W, att, bn_g, bn_b, bn_m, bn_v, eidx, slot, outj, expa);
    k_aggr<<<dim3(NN / 4), dim3(256), 0, stream>>>(offs, outj, expa, bias, out);
}